// Round 5
// baseline (30.829 us; speedup 1.0000x reference)
//
#include <hip/hip_runtime.h>

#define HH 512
#define WW 512
#define NB 8
constexpr int   NPIX = HH * WW;              // 262144 pixels per batch
constexpr int   FH   = (HH - 1) * (WW - 1);  // 261121 lower faces per batch
constexpr int   NF   = 2 * FH;               // 522242 faces per batch
constexpr float EPS       = 0.04f;
constexpr float DEPTH_MIN = 0.1f;
constexpr float EDGE_MAX  = 0.1f;

__device__ __forceinline__ float elen(float ax, float ay, float az,
                                      float bx, float by, float bz) {
    float dx = ax - bx, dy = ay - by, dz = az - bz;
    return sqrtf(dx * dx + dy * dy + dz * dz);
}

// per-wave LDS -> global copy of n floats; d is 4B-aligned, head fixup to 16B.
// Single-wave workgroup: wave-ordered DS, no barrier needed.
__device__ __forceinline__ void wcopy(const float* __restrict__ s,
                                      float* __restrict__ d, int n, int lane) {
    int head = (int)(((16u - (unsigned)((uintptr_t)d & 15u)) & 15u) >> 2);
    if (head > n) head = n;
    if (lane < head) d[lane] = s[lane];
    int n4 = (n - head) >> 2;
    const float* s2 = s + head;
    float* d2 = d + head;            // 16B aligned
    for (int i = lane; i < n4; i += 64) {
        float4 t = make_float4(s2[4*i], s2[4*i+1], s2[4*i+2], s2[4*i+3]);
        *(float4*)(d2 + 4*i) = t;    // 1024B contiguous per instruction
    }
    int done = n4 << 2;
    int rem  = n - head - done;
    if (lane < rem) d2[done + lane] = s2[done + lane];
}

// One wave (= one 64-thread workgroup) = (batch b, face-row y).
// Lane owns cols 4*lane + 256*g + j, g=0..1, j=0..3 -> all b128 loads/ds-writes.
__global__ void __launch_bounds__(64)
fused_kernel(const float* __restrict__ attr_d,
             const float* __restrict__ c2w_int,
             const float* __restrict__ c2w_ext,
             float* __restrict__ out_v,
             float* __restrict__ out_a,
             float* __restrict__ out_e,
             float* __restrict__ out_m) {
    __shared__ float ldsA[1536];
    __shared__ float ldsB[1536];
    const int lane = threadIdx.x;
    const int task = blockIdx.x;             // b*511 + y
    const int b    = task / 511;
    const int y    = task - b * 511;

    const float* base = attr_d + (size_t)b * 4 * NPIX;   // planar (C,H,W)
    const float* zr0  = base + 3 * NPIX + (size_t)y * WW;

    float z0[2][4], z1[2][4], a0[3][2][4];
#pragma unroll
    for (int g = 0; g < 2; ++g) {
        int c = (g << 8) + (lane << 2);
        float4 t0 = *(const float4*)(zr0 + c);
        float4 t1 = *(const float4*)(zr0 + WW + c);
        z0[g][0]=t0.x; z0[g][1]=t0.y; z0[g][2]=t0.z; z0[g][3]=t0.w;
        z1[g][0]=t1.x; z1[g][1]=t1.y; z1[g][2]=t1.z; z1[g][3]=t1.w;
    }
#pragma unroll
    for (int ch = 0; ch < 3; ++ch) {
        const float* ar = base + ch * NPIX + (size_t)y * WW;
#pragma unroll
        for (int g = 0; g < 2; ++g) {
            float4 t = *(const float4*)(ar + (g << 8) + (lane << 2));
            a0[ch][g][0]=t.x; a0[ch][g][1]=t.y; a0[ch][g][2]=t.z; a0[ch][g][3]=t.w;
        }
    }
    // col-511 attribute extension (rows 0..510; y<=510 here). Neighbor col 510
    // is lane-local element [1][2].
    if (lane == 63) {
#pragma unroll
        for (int ch = 0; ch < 3; ++ch)
            a0[ch][1][3] += (a0[ch][1][3] - a0[ch][1][2]) * EPS;
    }

    const float* K = c2w_int + b * 9;
    const float* E = c2w_ext + b * 12;
    const float K0=K[0],K1=K[1],K2=K[2],K3=K[3],K4=K[4],K5=K[5],K6=K[6],K7=K[7],K8=K[8];
    const float E0=E[0],E1=E[1],E2=E[2],E3=E[3],E4=E[4],E5=E[5],
                E6=E[6],E7=E[7],E8=E[8],E9=E[9],E10=E[10],E11=E[11];

    const float yc0 = (float)y + 0.5f;
    const float yc1 = (y + 1 == HH - 1) ? ((float)HH - 0.5f + EPS)
                                        : ((float)(y + 1) + 0.5f);

    float v0x[2][4], v0y[2][4], v0z[2][4], v1x[2][4], v1y[2][4], v1z[2][4];
#pragma unroll
    for (int g = 0; g < 2; ++g) {
#pragma unroll
        for (int j = 0; j < 4; ++j) {
            int col = (g << 8) + (lane << 2) + j;
            float xc = (col == WW - 1) ? ((float)WW - 0.5f + EPS)
                                       : ((float)col + 0.5f);
            {
                float zz = z0[g][j];
                float p0 = xc*zz, p1 = yc0*zz;
                float vi0 = K0*p0 + K1*p1 + K2*zz;
                float vi1 = K3*p0 + K4*p1 + K5*zz;
                float vi2 = K6*p0 + K7*p1 + K8*zz;
                v0x[g][j] = E0*vi0 + E1*vi1 + E2 *vi2 + E3;
                v0y[g][j] = E4*vi0 + E5*vi1 + E6 *vi2 + E7;
                v0z[g][j] = E8*vi0 + E9*vi1 + E10*vi2 + E11;
            }
            {
                float zz = z1[g][j];
                float p0 = xc*zz, p1 = yc1*zz;
                float vi0 = K0*p0 + K1*p1 + K2*zz;
                float vi1 = K3*p0 + K4*p1 + K5*zz;
                float vi2 = K6*p0 + K7*p1 + K8*zz;
                v1x[g][j] = E0*vi0 + E1*vi1 + E2 *vi2 + E3;
                v1y[g][j] = E4*vi0 + E5*vi1 + E6 *vi2 + E7;
                v1z[g][j] = E8*vi0 + E9*vi1 + E10*vi2 + E11;
            }
        }
    }

    float4* A4 = (float4*)ldsA;
    float4* B4 = (float4*)ldsB;

    // ---- v row y, a row y: 48B-contiguous b128 ds_writes -> coalesced wcopy
    size_t rb = ((size_t)b * NPIX + (size_t)y * WW) * 3;   // 16B aligned
#pragma unroll
    for (int g = 0; g < 2; ++g) {
        int o = 192*g + 3*lane;
        A4[o]   = make_float4(v0x[g][0], v0y[g][0], v0z[g][0], v0x[g][1]);
        A4[o+1] = make_float4(v0y[g][1], v0z[g][1], v0x[g][2], v0y[g][2]);
        A4[o+2] = make_float4(v0z[g][2], v0x[g][3], v0y[g][3], v0z[g][3]);
    }
    wcopy(ldsA, out_v + rb, 1536, lane);
#pragma unroll
    for (int g = 0; g < 2; ++g) {
        int o = 192*g + 3*lane;
        A4[o]   = make_float4(a0[0][g][0], a0[1][g][0], a0[2][g][0], a0[0][g][1]);
        A4[o+1] = make_float4(a0[1][g][1], a0[2][g][1], a0[0][g][2], a0[1][g][2]);
        A4[o+2] = make_float4(a0[2][g][2], a0[0][g][3], a0[1][g][3], a0[2][g][3]);
    }
    wcopy(ldsA, out_a + rb, 1536, lane);

    // ---- wave y==510 also owns pixel row 511 (v from v1, extended a)
    if (y == HH - 2) {
        float a1[3][2][4];
#pragma unroll
        for (int ch = 0; ch < 3; ++ch) {
            const float* ar = base + ch * NPIX + (size_t)(HH-1) * WW;
#pragma unroll
            for (int g = 0; g < 2; ++g) {
                float4 t = *(const float4*)(ar + (g << 8) + (lane << 2));
                a1[ch][g][0]=t.x; a1[ch][g][1]=t.y; a1[ch][g][2]=t.z; a1[ch][g][3]=t.w;
            }
#pragma unroll
            for (int g = 0; g < 2; ++g)
#pragma unroll
            for (int j = 0; j < 4; ++j) {
                int col = (g << 8) + (lane << 2) + j;
                if (col < WW - 1)                       // last-row rule, cols 0..510
                    a1[ch][g][j] += (a1[ch][g][j] - a0[ch][g][j]) * EPS;
            }
            if (lane == 63)                             // corner: diag a[510][510]
                a1[ch][1][3] += (a1[ch][1][3] - a0[ch][1][2]) * EPS;
        }
        size_t rb1 = ((size_t)b * NPIX + (size_t)(HH-1) * WW) * 3;
#pragma unroll
        for (int g = 0; g < 2; ++g) {
            int o = 192*g + 3*lane;
            A4[o]   = make_float4(v1x[g][0], v1y[g][0], v1z[g][0], v1x[g][1]);
            A4[o+1] = make_float4(v1y[g][1], v1z[g][1], v1x[g][2], v1y[g][2]);
            A4[o+2] = make_float4(v1z[g][2], v1x[g][3], v1y[g][3], v1z[g][3]);
        }
        wcopy(ldsA, out_v + rb1, 1536, lane);
#pragma unroll
        for (int g = 0; g < 2; ++g) {
            int o = 192*g + 3*lane;
            A4[o]   = make_float4(a1[0][g][0], a1[1][g][0], a1[2][g][0], a1[0][g][1]);
            A4[o+1] = make_float4(a1[1][g][1], a1[2][g][1], a1[0][g][2], a1[1][g][2]);
            A4[o+2] = make_float4(a1[2][g][2], a1[0][g][3], a1[1][g][3], a1[2][g][3]);
        }
        wcopy(ldsA, out_a + rb1, 1536, lane);
    }

    // ---- edges + masks
    float vert[2][4];
#pragma unroll
    for (int g = 0; g < 2; ++g)
#pragma unroll
    for (int j = 0; j < 4; ++j)
        vert[g][j] = elen(v0x[g][j],v0y[g][j],v0z[g][j],
                          v1x[g][j],v1y[g][j],v1z[g][j]);

    // boundary neighbor (col = 4*lane+3+1): lane+1's elem0 of same g;
    // lane63 g0 wraps to lane0's g1 elem0; lane63 g1 is col 511 (unused).
    float n0x[2],n0y[2],n0z[2],n1x[2],n1y[2],n1z[2],nz0[2],nz1[2],nvt[2];
#pragma unroll
    for (int g = 0; g < 2; ++g) {
        int src = (lane + 1) & 63;
#define NBR(dst, arr) { float s_ = (g == 0 && lane == 0) ? arr[1][0] : arr[g][0]; \
                        dst[g] = __shfl(s_, src); }
        NBR(n0x, v0x) NBR(n0y, v0y) NBR(n0z, v0z)
        NBR(n1x, v1x) NBR(n1y, v1y) NBR(n1z, v1z)
        NBR(nz0, z0)  NBR(nz1, z1)  NBR(nvt, vert)
#undef NBR
    }

    float mlv[2][4], muv[2][4];
#pragma unroll
    for (int g = 0; g < 2; ++g) {
        float tp[4], bt[4], dg[4], vn[4];
#pragma unroll
        for (int j = 0; j < 4; ++j) {
            float px0 = (j<3)? v0x[g][j+1] : n0x[g];
            float py0 = (j<3)? v0y[g][j+1] : n0y[g];
            float pz0 = (j<3)? v0z[g][j+1] : n0z[g];
            float px1 = (j<3)? v1x[g][j+1] : n1x[g];
            float py1 = (j<3)? v1y[g][j+1] : n1y[g];
            float pz1 = (j<3)? v1z[g][j+1] : n1z[g];
            float zt1 = (j<3)? z0[g][j+1]  : nz0[g];
            float zb1 = (j<3)? z1[g][j+1]  : nz1[g];
            vn[j]     = (j<3)? vert[g][j+1] : nvt[g];
            tp[j] = elen(v0x[g][j],v0y[g][j],v0z[g][j], px0,py0,pz0);
            bt[j] = elen(v1x[g][j],v1y[g][j],v1z[g][j], px1,py1,pz1);
            dg[j] = elen(v0x[g][j],v0y[g][j],v0z[g][j], px1,py1,pz1);
            bool ml = (z0[g][j] > DEPTH_MIN) & (z1[g][j] > DEPTH_MIN) & (zb1 > DEPTH_MIN) &
                      (vert[g][j] < EDGE_MAX) & (bt[j] < EDGE_MAX) & (dg[j] < EDGE_MAX);
            bool mu = (z0[g][j] > DEPTH_MIN) & (zb1 > DEPTH_MIN) & (zt1 > DEPTH_MIN) &
                      (dg[j] < EDGE_MAX) & (vn[j] < EDGE_MAX) & (tp[j] < EDGE_MAX);
            mlv[g][j] = ml ? 1.0f : 0.0f;
            muv[g][j] = mu ? 1.0f : 0.0f;
        }
        int o = 192*g + 3*lane;
        A4[o]   = make_float4(vert[g][0], bt[0], dg[0], vert[g][1]);   // e_lo
        A4[o+1] = make_float4(bt[1], dg[1], vert[g][2], bt[2]);
        A4[o+2] = make_float4(dg[2], vert[g][3], bt[3], dg[3]);
        B4[o]   = make_float4(dg[0], vn[0], tp[0], dg[1]);             // e_up
        B4[o+1] = make_float4(vn[1], tp[1], dg[2], vn[2]);
        B4[o+2] = make_float4(tp[2], dg[3], vn[3], tp[3]);
    }
    size_t mlo = (size_t)b * NF + (size_t)y * (WW - 1);
    size_t mup = mlo + FH;
    wcopy(ldsA, out_e + mlo * 3, 1533, lane);
    wcopy(ldsB, out_e + mup * 3, 1533, lane);

    // masks (reuse ldsA after its reads are done; wave-ordered)
#pragma unroll
    for (int g = 0; g < 2; ++g) {
        A4[(g << 6) + lane]       = make_float4(mlv[g][0], mlv[g][1], mlv[g][2], mlv[g][3]);
        A4[128 + (g << 6) + lane] = make_float4(muv[g][0], muv[g][1], muv[g][2], muv[g][3]);
    }
    wcopy(ldsA,       out_m + mlo, 511, lane);
    wcopy(ldsA + 512, out_m + mup, 511, lane);
}

extern "C" void kernel_launch(void* const* d_in, const int* in_sizes, int n_in,
                              void* d_out, int out_size, void* d_ws, size_t ws_size,
                              hipStream_t stream) {
    const float* attr_d  = (const float*)d_in[0];
    const float* c2w_int = (const float*)d_in[1];
    const float* c2w_ext = (const float*)d_in[2];

    float* out   = (float*)d_out;
    float* out_v = out;                                  // B*N*3
    float* out_a = out + (size_t)NB * NPIX * 3;          // B*N*3
    float* out_e = out + (size_t)2 * NB * NPIX * 3;      // B*F*3
    float* out_m = out_e + (size_t)NB * NF * 3;          // B*F

    int tasks = NB * (HH - 1);                           // 4088 wave-tasks
    fused_kernel<<<tasks, 64, 0, stream>>>(attr_d, c2w_int, c2w_ext,
                                           out_v, out_a, out_e, out_m);
}